// Round 7
// baseline (236.548 us; speedup 1.0000x reference)
//
#include <hip/hip_runtime.h>
#include <hip/hip_bf16.h>
#include <cstdint>

#define B_ 2
#define C_ 128
#define E_ 60000

typedef unsigned int uint32_;
typedef unsigned short ushort_;
typedef float v2f __attribute__((ext_vector_type(2)));

// unpack two bf16 (dword: low = ch0, high = ch1) to packed float2
__device__ __forceinline__ v2f bp2(uint32_ v) {
    v2f r;
    r.x = __uint_as_float(v << 16);
    r.y = __uint_as_float(v & 0xffff0000u);
    return r;
}

__device__ __forceinline__ v2f vabs2(v2f a) {
    v2f r; r.x = fabsf(a.x); r.y = fabsf(a.y); return r;
}

// float -> bf16 round-to-nearest-even
__device__ __forceinline__ ushort_ f2b(float f) {
    union { float f; uint32_ u; } x; x.f = f;
    uint32_ u = x.u + 0x7fffu + ((x.u >> 16) & 1u);
    return (ushort_)(u >> 16);
}

__device__ __forceinline__ uint32_ packb(float lo, float hi) {
    return (uint32_)f2b(lo) | ((uint32_)f2b(hi) << 16);
}

// within-32-lane-group xor-add via ds_swizzle (and_mask 0x1F keeps halves separate)
__device__ __forceinline__ float swz_add(float v, const int pat) {
    switch (pat) {
    case 1:  return v + __int_as_float(__builtin_amdgcn_ds_swizzle(__float_as_int(v), 0x041F));
    case 2:  return v + __int_as_float(__builtin_amdgcn_ds_swizzle(__float_as_int(v), 0x081F));
    case 4:  return v + __int_as_float(__builtin_amdgcn_ds_swizzle(__float_as_int(v), 0x101F));
    case 8:  return v + __int_as_float(__builtin_amdgcn_ds_swizzle(__float_as_int(v), 0x201F));
    default: return v + __int_as_float(__builtin_amdgcn_ds_swizzle(__float_as_int(v), 0x401F));
    }
}

// ---------------------------------------------------------------------------
// Kernel 0: fold the 256->3 fuse conv into per-path weights (wave-parallel).
// Vw layout: [p][j][s][c] flat (s=0 absorbs the local conv). cst[j] = biases.
// Grid must be 16 blocks (blocks 0..14 = 60 waves of Vw work, block 15 = cst).
// ---------------------------------------------------------------------------
__global__ __launch_bounds__(256) void fuse_weights_kernel(
    const float* __restrict__ Wa_local, const float* __restrict__ ba_local,
    const float* __restrict__ Wb_local, const float* __restrict__ bb_local,
    const float* __restrict__ Wa_tri,  const float* __restrict__ ba_tri,
    const float* __restrict__ Wb_tri,  const float* __restrict__ bb_tri,
    const float* __restrict__ Wa_fuse, const float* __restrict__ ba_fuse,
    const float* __restrict__ Wb_fuse, const float* __restrict__ bb_fuse,
    float* __restrict__ Vw, float* __restrict__ cst)
{
    const int lane = threadIdx.x & 63;
    if (blockIdx.x < 15) {
        const int wid   = blockIdx.x * 4 + (threadIdx.x >> 6); // 0..59
        const int pj    = wid / 10;                            // 0..5
        const int chunk = wid % 10;                            // 0..9
        const int p = pj / 3, j = pj % 3;
        const int f = chunk * 64 + lane;                       // 0..639 = c*5+s
        const float* Wf = p ? Wb_fuse : Wa_fuse;   // [3][256]
        const float* Wt = p ? Wb_tri  : Wa_tri;    // [128][128][5] flat o*640+f
        const float* Wl = p ? Wb_local : Wa_local; // [128][128]
        float a0 = 0.f, a1 = 0.f, a2 = 0.f, a3 = 0.f;
        for (int o = 0; o < C_; o += 4) {
            a0 += Wf[j * 256 + 128 + o]     * Wt[(o)     * 640 + f];
            a1 += Wf[j * 256 + 128 + o + 1] * Wt[(o + 1) * 640 + f];
            a2 += Wf[j * 256 + 128 + o + 2] * Wt[(o + 2) * 640 + f];
            a3 += Wf[j * 256 + 128 + o + 3] * Wt[(o + 3) * 640 + f];
        }
        float acc = (a0 + a1) + (a2 + a3);
        const int s = f % 5, c = f / 5;
        if (s == 0) {   // absorb the local conv into the s=0 slot
            float b0 = 0.f, b1 = 0.f, b2 = 0.f, b3 = 0.f;
            for (int o = 0; o < C_; o += 4) {
                b0 += Wf[j * 256 + o]     * Wl[(o)     * C_ + c];
                b1 += Wf[j * 256 + o + 1] * Wl[(o + 1) * C_ + c];
                b2 += Wf[j * 256 + o + 2] * Wl[(o + 2) * C_ + c];
                b3 += Wf[j * 256 + o + 3] * Wl[(o + 3) * C_ + c];
            }
            acc += (b0 + b1) + (b2 + b3);
        }
        Vw[(pj * 5 + s) * C_ + c] = acc;
    } else {
        if (threadIdx.x < 3) {
            int j = threadIdx.x;
            float acc = ba_fuse[j] + bb_fuse[j];
            for (int o = 0; o < C_; ++o) {
                acc += Wa_fuse[j * 256 + o]       * ba_local[o]
                     + Wa_fuse[j * 256 + 128 + o] * ba_tri[o]
                     + Wb_fuse[j * 256 + o]       * bb_local[o]
                     + Wb_fuse[j * 256 + 128 + o] * bb_tri[o];
            }
            cst[j] = acc;
        }
    }
}

// ---------------------------------------------------------------------------
// Kernel 1: transpose+quantize BOTH inputs into one interleaved buffer.
// y row for (b,e) = 128 dwords: dword 2p = x0 bf16-pair p, 2p+1 = x1 pair p.
// 64e x 64c tile (8 dwordx4 in flight per thread). Tail block clamps loads
// and guards stores (E_=60000 is not a multiple of 64).
// ---------------------------------------------------------------------------
__global__ __launch_bounds__(256) void transpose_interleave_kernel(
    const float* __restrict__ x0, const float* __restrict__ x1,
    uint32_* __restrict__ y)
{
    __shared__ float tA[64][65];
    __shared__ float tB[64][65];
    const int b  = blockIdx.z;
    const int e0 = blockIdx.x * 64;
    const int c0 = blockIdx.y * 64;
    const float* s0 = x0 + (size_t)b * C_ * E_ + (size_t)c0 * E_;
    const float* s1 = x1 + (size_t)b * C_ * E_ + (size_t)c0 * E_;
    const int t = threadIdx.x;
    {
        const int c   = t >> 2;          // 0..63 local channel
        const int e16 = (t & 3) * 16;    // 0,16,32,48
        const float* p0 = s0 + (size_t)c * E_;
        const float* p1 = s1 + (size_t)c * E_;
#pragma unroll
        for (int i = 0; i < 4; ++i) {
            int ea = e0 + e16 + 4 * i;
            ea = (ea > E_ - 4) ? (E_ - 4) : ea;   // tail clamp; stores guarded
            float4 u = *(const float4*)(p0 + ea);
            float4 v = *(const float4*)(p1 + ea);
            const int el = e16 + 4 * i;
            tA[el + 0][c] = u.x; tA[el + 1][c] = u.y;
            tA[el + 2][c] = u.z; tA[el + 3][c] = u.w;
            tB[el + 0][c] = v.x; tB[el + 1][c] = v.y;
            tB[el + 2][c] = v.z; tB[el + 3][c] = v.w;
        }
    }
    __syncthreads();
    {
        const int e   = t >> 2;          // 0..63 local edge row
        const int k16 = (t & 3) * 16;    // dword offset in the 64-dword half
        const int er  = e0 + e;
        if (er < E_) {
            const float* ra = &tA[e][k16];
            const float* rb = &tB[e][k16];
            uint32_* drow = y + (((size_t)(b * E_ + er)) << 7) + c0 + k16;
#pragma unroll
            for (int m = 0; m < 4; ++m) {
                uint4 w_;
                w_.x = packb(ra[4 * m],     ra[4 * m + 1]);
                w_.y = packb(rb[4 * m],     rb[4 * m + 1]);
                w_.z = packb(ra[4 * m + 2], ra[4 * m + 3]);
                w_.w = packb(rb[4 * m + 2], rb[4 * m + 3]);
                *(uint4*)(drow + 4 * m) = w_;
            }
        }
    }
}

// ---------------------------------------------------------------------------
// Kernel 2: fused gather + features + 3-channel projection.
// Software-pipelined: iteration i+1's 10 dwordx2 gathers are issued before
// iteration i's compute, so compute overlaps L3 gather latency. Weights live
// in 30 named v2f registers (launch_bounds(256,3) gives the VGPR headroom).
// ---------------------------------------------------------------------------
#define LDW(p, j, s) (*(const v2f*)(Vw + ((((p) * 3 + (j)) * 5 + (s)) << 7) + (lane << 1)))

#define ISSUE(B0,B1,B2,B3,B4,B5,B6,B7,B8,B9, gA, gB, pr) do {                 \
    const int ee0_ = 2 * (pr);                                                \
    const int bb_  = (ee0_ >= E_) ? 1 : 0;                                    \
    const int ee_  = ee0_ - (bb_ ? E_ : 0);                                   \
    const uint2* Yb_ = yy + (size_t)bb_ * (E_ * 64);                          \
    const uint32_ s0_ = ((uint32_)ee_ << 6) + lane;                           \
    B1 = Yb_[((uint32_)(gA).x << 6) + lane];                                  \
    B2 = Yb_[((uint32_)(gA).y << 6) + lane];                                  \
    B3 = Yb_[((uint32_)(gA).z << 6) + lane];                                  \
    B4 = Yb_[((uint32_)(gA).w << 6) + lane];                                  \
    B6 = Yb_[((uint32_)(gB).x << 6) + lane];                                  \
    B7 = Yb_[((uint32_)(gB).y << 6) + lane];                                  \
    B8 = Yb_[((uint32_)(gB).z << 6) + lane];                                  \
    B9 = Yb_[((uint32_)(gB).w << 6) + lane];                                  \
    B0 = Yb_[s0_];                                                            \
    B5 = Yb_[s0_ + 64];                                                       \
} while (0)

#define EDGE_DOT(P0,P1,P2,P3,P4, R0,R1,R2) do {                               \
    v2f a0 = bp2(P0.x), a1 = bp2(P1.x), a2 = bp2(P2.x),                       \
        a3 = bp2(P3.x), a4 = bp2(P4.x);                                       \
    v2f b0 = bp2(P0.y), b1 = bp2(P1.y), b2 = bp2(P2.y),                       \
        b3 = bp2(P3.y), b4 = bp2(P4.y);                                       \
    v2f sa1 = a1 + a3, sa2 = a2 + a4;                                         \
    v2f da1 = vabs2(a1 - a3), da2 = vabs2(a2 - a4);                           \
    v2f sb1 = b1 + b3, sb2 = b2 + b4;                                         \
    v2f db1 = vabs2(b1 - b3), db2 = vabs2(b2 - b4);                           \
    v2f t0 = w000 * a0 + w001 * sa1 + w002 * sa2 + w003 * da1 + w004 * da2    \
           + w100 * b0 + w101 * sb1 + w102 * sb2 + w103 * db1 + w104 * db2;   \
    v2f t1 = w010 * a0 + w011 * sa1 + w012 * sa2 + w013 * da1 + w014 * da2    \
           + w110 * b0 + w111 * sb1 + w112 * sb2 + w113 * db1 + w114 * db2;   \
    v2f t2 = w020 * a0 + w021 * sa1 + w022 * sa2 + w023 * da1 + w024 * da2    \
           + w120 * b0 + w121 * sb1 + w122 * sb2 + w123 * db1 + w124 * db2;   \
    R0 = t0.x + t0.y; R1 = t1.x + t1.y; R2 = t2.x + t2.y;                     \
} while (0)

#define COMPSTORE(B0,B1,B2,B3,B4,B5,B6,B7,B8,B9, pr) do {                     \
    float rA0, rA1, rA2, rB0, rB1, rB2;                                       \
    EDGE_DOT(B0, B1, B2, B3, B4, rA0, rA1, rA2);                              \
    EDGE_DOT(B5, B6, B7, B8, B9, rB0, rB1, rB2);                              \
    rA0 = swz_add(rA0, 16); rB0 = swz_add(rB0, 16);                           \
    rA1 = swz_add(rA1, 16); rB1 = swz_add(rB1, 16);                           \
    rA2 = swz_add(rA2, 16); rB2 = swz_add(rB2, 16);                           \
    rA0 += __shfl_xor(rA0, 32, 64); rB0 += __shfl_xor(rB0, 32, 64);           \
    rA1 += __shfl_xor(rA1, 32, 64); rB1 += __shfl_xor(rB1, 32, 64);           \
    rA2 += __shfl_xor(rA2, 32, 64); rB2 += __shfl_xor(rB2, 32, 64);           \
    float vA = is0 ? rA0 : (is1 ? rA1 : rA2);                                 \
    float vB = is0 ? rB0 : (is1 ? rB1 : rB2);                                 \
    vA = swz_add(vA, 1); vB = swz_add(vB, 1);                                 \
    vA = swz_add(vA, 2); vB = swz_add(vB, 2);                                 \
    vA = swz_add(vA, 4); vB = swz_add(vB, 4);                                 \
    vA = swz_add(vA, 8); vB = swz_add(vB, 8);                                 \
    if (writer) {                                                             \
        const int ee0_ = 2 * (pr);                                            \
        const int bb_  = (ee0_ >= E_) ? 1 : 0;                                \
        const int ee_  = ee0_ - (bb_ ? E_ : 0);                               \
        float2 st; st.x = vA + cj; st.y = vB + cj;                            \
        *(float2*)(obase + (bb_ ? 3 * E_ : 0) + ee_) = st;                    \
    }                                                                         \
} while (0)

__global__ __launch_bounds__(256, 3) void mesh_fused_kernel(
    const uint2* __restrict__ yy, const int* __restrict__ gemm,
    const float* __restrict__ Vw, const float* __restrict__ cst,
    float* __restrict__ out)
{
    const int lane = threadIdx.x & 63;
    const int wv   = threadIdx.x >> 6;
    const int gw   = blockIdx.x * 4 + wv;
    const int nw   = gridDim.x * 4;

    // 30 named weight registers (keep out of arrays so they stay in VGPRs)
    v2f w000 = LDW(0,0,0), w001 = LDW(0,0,1), w002 = LDW(0,0,2),
        w003 = LDW(0,0,3), w004 = LDW(0,0,4);
    v2f w010 = LDW(0,1,0), w011 = LDW(0,1,1), w012 = LDW(0,1,2),
        w013 = LDW(0,1,3), w014 = LDW(0,1,4);
    v2f w020 = LDW(0,2,0), w021 = LDW(0,2,1), w022 = LDW(0,2,2),
        w023 = LDW(0,2,3), w024 = LDW(0,2,4);
    v2f w100 = LDW(1,0,0), w101 = LDW(1,0,1), w102 = LDW(1,0,2),
        w103 = LDW(1,0,3), w104 = LDW(1,0,4);
    v2f w110 = LDW(1,1,0), w111 = LDW(1,1,1), w112 = LDW(1,1,2),
        w113 = LDW(1,1,3), w114 = LDW(1,1,4);
    v2f w120 = LDW(1,2,0), w121 = LDW(1,2,1), w122 = LDW(1,2,2),
        w123 = LDW(1,2,3), w124 = LDW(1,2,4);

    const int  jj     = lane >> 4;                 // 0..3
    const bool is0    = (jj == 0), is1 = (jj == 1);
    const bool writer = ((lane & 15) == 0) && (jj < 3);
    const float cj    = is0 ? cst[0] : (is1 ? cst[1] : cst[2]);
    float* obase      = out + (size_t)(jj < 3 ? jj : 2) * E_;

    const int4* g4 = (const int4*)gemm;
    const int npair = (B_ * E_) / 2;

    int pc = gw;
    if (pc >= npair) return;

    uint2 A0, A1, A2, A3, A4, A5, A6, A7, A8, A9;   // buffer A
    uint2 D0, D1, D2, D3, D4, D5, D6, D7, D8, D9;   // buffer B

    int4 giA = g4[2 * pc], giB = g4[2 * pc + 1];
    ISSUE(A0,A1,A2,A3,A4,A5,A6,A7,A8,A9, giA, giB, pc);
    int pn = pc + nw;
    if (pn < npair) { giA = g4[2 * pn]; giB = g4[2 * pn + 1]; }

    for (;;) {
        // ---- stage 1: bufA holds pc; load pn into bufB ----
        if (pn >= npair) { COMPSTORE(A0,A1,A2,A3,A4,A5,A6,A7,A8,A9, pc); break; }
        ISSUE(D0,D1,D2,D3,D4,D5,D6,D7,D8,D9, giA, giB, pn);
        {
            const int pf = pn + nw;
            if (pf < npair) { giA = g4[2 * pf]; giB = g4[2 * pf + 1]; }
            COMPSTORE(A0,A1,A2,A3,A4,A5,A6,A7,A8,A9, pc);
            pc = pn; pn = pf;
        }
        // ---- stage 2: bufB holds pc; load pn into bufA ----
        if (pn >= npair) { COMPSTORE(D0,D1,D2,D3,D4,D5,D6,D7,D8,D9, pc); break; }
        ISSUE(A0,A1,A2,A3,A4,A5,A6,A7,A8,A9, giA, giB, pn);
        {
            const int pf = pn + nw;
            if (pf < npair) { giA = g4[2 * pf]; giB = g4[2 * pf + 1]; }
            COMPSTORE(D0,D1,D2,D3,D4,D5,D6,D7,D8,D9, pc);
            pc = pn; pn = pf;
        }
    }
}

extern "C" void kernel_launch(void* const* d_in, const int* in_sizes, int n_in,
                              void* d_out, int out_size, void* d_ws, size_t ws_size,
                              hipStream_t stream) {
    const float* x0       = (const float*)d_in[0];
    const float* x1       = (const float*)d_in[1];
    const int*   gemm     = (const int*)d_in[2];
    const float* Wa_local = (const float*)d_in[3];
    const float* ba_local = (const float*)d_in[4];
    const float* Wb_local = (const float*)d_in[5];
    const float* bb_local = (const float*)d_in[6];
    const float* Wa_tri   = (const float*)d_in[7];
    const float* ba_tri   = (const float*)d_in[8];
    const float* Wb_tri   = (const float*)d_in[9];
    const float* bb_tri   = (const float*)d_in[10];
    const float* Wa_fuse  = (const float*)d_in[11];
    const float* ba_fuse  = (const float*)d_in[12];
    const float* Wb_fuse  = (const float*)d_in[13];
    const float* bb_fuse  = (const float*)d_in[14];
    float* out = (float*)d_out;

    uint32_* y   = (uint32_*)d_ws;                        // B*E*128 dwords
    float*   Vw  = (float*)(y + (size_t)B_ * E_ * 128);
    float*   cst = Vw + 2 * 3 * 5 * C_;

    hipLaunchKernelGGL(fuse_weights_kernel, dim3(16), dim3(256), 0, stream,
                       Wa_local, ba_local, Wb_local, bb_local,
                       Wa_tri, ba_tri, Wb_tri, bb_tri,
                       Wa_fuse, ba_fuse, Wb_fuse, bb_fuse, Vw, cst);

    hipLaunchKernelGGL(transpose_interleave_kernel,
                       dim3((E_ + 63) / 64, C_ / 64, B_),
                       dim3(256), 0, stream, x0, x1, y);

    hipLaunchKernelGGL(mesh_fused_kernel, dim3(2048), dim3(256), 0, stream,
                       (const uint2*)y, gemm, Vw, cst, out);
}